// Round 6
// baseline (34.036 us; speedup 1.0000x reference)
//
#include <hip/hip_runtime.h>
#include <math.h>

#define B_ 4096
#define D_ 256
#define C_ 64
#define BD (B_*D_)

__device__ __forceinline__ float wave_reduce_sum(float v) {
    #pragma unroll
    for (int off = 1; off < 64; off <<= 1) v += __shfl_xor(v, off);
    return v;
}

// full sum across each aligned 16-lane group, result in all 16 lanes (VALU-only DPP)
__device__ __forceinline__ float dpp_sum16(float v) {
    int t;
    t = __builtin_amdgcn_update_dpp(0, __float_as_int(v), 0x121, 0xF, 0xF, true); v += __int_as_float(t); // ror:1
    t = __builtin_amdgcn_update_dpp(0, __float_as_int(v), 0x122, 0xF, 0xF, true); v += __int_as_float(t); // ror:2
    t = __builtin_amdgcn_update_dpp(0, __float_as_int(v), 0x124, 0xF, 0xF, true); v += __int_as_float(t); // ror:4
    t = __builtin_amdgcn_update_dpp(0, __float_as_int(v), 0x128, 0xF, 0xF, true); v += __int_as_float(t); // ror:8
    return v;
}

// ---- fused: x-copy stripe + Sum(x^2) partial, local bucket scan (overlapping
//      the W HBM load), W-L1 partial, grouped matvec with prefetched x tiles.
//      grid = 64 conds x 4 ot x 2 sample-halves ----
__global__ __launch_bounds__(256) void k_main(const float* __restrict__ W,
                                              const float* __restrict__ b,
                                              const float* __restrict__ x,
                                              const int* __restrict__ c,
                                              float* __restrict__ out,
                                              float* __restrict__ l1p,
                                              float* __restrict__ xsqp,
                                              int* __restrict__ cnt2) {
    int hw = blockIdx.x;
    int bid = (hw & 7) * 64 + (hw >> 3);    // XCD swizzle: 64 consecutive logical blocks per XCD
    int cond = bid >> 3;
    int ot = (bid >> 1) & 3;
    int sl2 = bid & 1;
    int tid = threadIdx.x;
    int rg = tid >> 4, kseg = tid & 15;
    int swz = kseg >> 1;
    int row0 = ot * 64 + rg * 4;

    // --- issue x-stripe + c loads FIRST, W loads after: early waits drain only x/c ---
    int xi = bid * 512 + tid;               // 2 float4 per thread, 262144 total
    float4 xv0 = ((const float4*)x)[xi];
    float4 xv1 = ((const float4*)x)[xi + 256];
    int4 cv[4];
    #pragma unroll
    for (int t = 0; t < 4; ++t) cv[t] = ((const int4*)c)[tid + 256 * t];

    float4 Wreg[4][4];                      // [row][k-float4]
    #pragma unroll
    for (int rr = 0; rr < 4; ++rr) {
        const float4* wp = (const float4*)(W + (size_t)cond * (D_ * D_) + (size_t)(row0 + rr) * D_ + kseg * 16);
        #pragma unroll
        for (int j = 0; j < 4; ++j) Wreg[rr][j] = wp[j];
    }

    __shared__ float part_x[4];
    __shared__ float part_w[4];
    __shared__ int slist[2048];
    __shared__ int nlist;
    if (tid == 0) nlist = 0;

    // x copy to out tail + sumsq partial (waits xv only; W stays in flight)
    float2* dst = (float2*)(out + BD + 2);
    dst[2 * xi]           = make_float2(xv0.x, xv0.y);
    dst[2 * xi + 1]       = make_float2(xv0.z, xv0.w);
    dst[2 * (xi + 256)]     = make_float2(xv1.x, xv1.y);
    dst[2 * (xi + 256) + 1] = make_float2(xv1.z, xv1.w);
    float s = xv0.x * xv0.x + xv0.y * xv0.y + xv0.z * xv0.z + xv0.w * xv0.w
            + xv1.x * xv1.x + xv1.y * xv1.y + xv1.z * xv1.z + xv1.w * xv1.w;
    s = wave_reduce_sum(s);
    int wid = tid >> 6, lane = tid & 63;
    if (lane == 0) part_x[wid] = s;
    __syncthreads();                         // nlist init + part_x visible

    // local bucket scan: half sl2 owns samples i mod 4 in {2*sl2, 2*sl2+1}
    #pragma unroll
    for (int t = 0; t < 4; ++t) {
        int4 q = cv[t];
        int c0 = sl2 ? q.z : q.x;
        int c1 = sl2 ? q.w : q.y;
        int bse = 4 * (tid + 256 * t) + 2 * sl2;
        if (c0 == cond) { int p = atomicAdd(&nlist, 1); slist[p] = bse; }
        if (c1 == cond) { int p = atomicAdd(&nlist, 1); slist[p] = bse + 1; }
    }

    // NOW pin W (vmcnt drain): latency was covered by the copy/scan above
    #pragma unroll
    for (int rr = 0; rr < 4; ++rr)
        #pragma unroll
        for (int j = 0; j < 4; ++j)
            asm volatile("" : "+v"(Wreg[rr][j].x), "+v"(Wreg[rr][j].y), "+v"(Wreg[rr][j].z), "+v"(Wreg[rr][j].w));

    if (sl2 == 0) {                          // |W| L1 partial (W counted exactly once overall)
        float a = 0.f;
        #pragma unroll
        for (int rr = 0; rr < 4; ++rr)
            #pragma unroll
            for (int j = 0; j < 4; ++j)
                a += fabsf(Wreg[rr][j].x) + fabsf(Wreg[rr][j].y) + fabsf(Wreg[rr][j].z) + fabsf(Wreg[rr][j].w);
        a = wave_reduce_sum(a);
        if (lane == 0) part_w[wid] = a;
    }
    __syncthreads();                         // scatter + part_w done
    int n = nlist;
    if (tid == 0) {
        xsqp[bid] = (part_x[0] + part_x[1]) + (part_x[2] + part_x[3]);
        if (sl2 == 0) l1p[cond * 4 + ot] = (part_w[0] + part_w[1]) + (part_w[2] + part_w[3]);
        if (ot == 0) cnt2[cond * 2 + sl2] = n;
    }

    float4 bias = ((const float4*)(b + cond * D_ + ot * 64))[rg];
    const float4* x4 = (const float4*)x;

    __shared__ float4 xs[16 * 64];
    int T = (n + 15) >> 4;
    float4 pre[4];
    // prefetch tile 0
    int ns0 = min(16, n);
    #pragma unroll
    for (int k = 0; k < 4; ++k) {
        int u = tid + 256 * k;
        if (u < ns0 * 64) {
            int si = u >> 6, v = u & 63;
            pre[k] = x4[(size_t)slist[si] * 64 + v];
        }
    }
    for (int t = 0; t < T; ++t) {
        int s0 = t * 16;
        int ns = min(16, n - s0);
        // write prefetched tile to LDS (swizzled)
        #pragma unroll
        for (int k = 0; k < 4; ++k) {
            int u = tid + 256 * k;
            if (u < ns * 64) {
                int si = u >> 6, v = u & 63;
                xs[si * 64 + (v & 0x3C) + (((v & 3) + (v >> 3)) & 3)] = pre[k];
            }
        }
        // issue NEXT tile's gather now — latency hides under compute below
        if (t + 1 < T) {
            int ns2 = min(16, n - s0 - 16);
            #pragma unroll
            for (int k = 0; k < 4; ++k) {
                int u = tid + 256 * k;
                if (u < ns2 * 64) {
                    int si = u >> 6, v = u & 63;
                    pre[k] = x4[(size_t)slist[s0 + 16 + si] * 64 + v];
                }
            }
        }
        __syncthreads();
        for (int si = 0; si < ns; ++si) {
            const float4* xp = &xs[si * 64 + kseg * 4];
            float4 a0 = make_float4(0.f, 0.f, 0.f, 0.f);
            float4 a1 = a0, a2 = a0, a3 = a0;
            #pragma unroll
            for (int jl = 0; jl < 4; ++jl) {
                float4 q = xp[(jl + swz) & 3];
                a0.x += Wreg[0][jl].x * q.x; a0.y += Wreg[0][jl].y * q.y;
                a0.z += Wreg[0][jl].z * q.z; a0.w += Wreg[0][jl].w * q.w;
                a1.x += Wreg[1][jl].x * q.x; a1.y += Wreg[1][jl].y * q.y;
                a1.z += Wreg[1][jl].z * q.z; a1.w += Wreg[1][jl].w * q.w;
                a2.x += Wreg[2][jl].x * q.x; a2.y += Wreg[2][jl].y * q.y;
                a2.z += Wreg[2][jl].z * q.z; a2.w += Wreg[2][jl].w * q.w;
                a3.x += Wreg[3][jl].x * q.x; a3.y += Wreg[3][jl].y * q.y;
                a3.z += Wreg[3][jl].z * q.z; a3.w += Wreg[3][jl].w * q.w;
            }
            float r0 = dpp_sum16((a0.x + a0.y) + (a0.z + a0.w));
            float r1 = dpp_sum16((a1.x + a1.y) + (a1.z + a1.w));
            float r2 = dpp_sum16((a2.x + a2.y) + (a2.z + a2.w));
            float r3 = dpp_sum16((a3.x + a3.y) + (a3.z + a3.w));
            if (kseg == 0) {
                int sg = slist[s0 + si];
                ((float4*)out)[(size_t)sg * 64 + ot * 16 + rg] =
                    make_float4(r0 + bias.x, r1 + bias.y, r2 + bias.z, r3 + bias.w);
            }
        }
        __syncthreads();
    }
}

// ---- blocks 0..1023: in-place row L2-normalize ----
// ---- block 1024: finalize embed_norm (xsqp) and mask_norm (l1p, cnt2) ----
__global__ __launch_bounds__(256) void k_finish(float* __restrict__ out,
                                                const float* __restrict__ xsqp,
                                                const float* __restrict__ l1p,
                                                const int* __restrict__ cnt2) {
    int tid = threadIdx.x;
    if (blockIdx.x == 1024) {
        __shared__ float part[4];
        float s = xsqp[tid] + xsqp[tid + 256];
        s = wave_reduce_sum(s);
        int wid = tid >> 6, lane = tid & 63;
        if (lane == 0) part[wid] = s;
        __syncthreads();
        if (tid < 64) {
            float l1 = (l1p[tid * 4 + 0] + l1p[tid * 4 + 1]) + (l1p[tid * 4 + 2] + l1p[tid * 4 + 3]);
            float cnt = (float)(cnt2[tid * 2] + cnt2[tid * 2 + 1]);
            float mv = l1 * cnt;
            mv = wave_reduce_sum(mv);
            if (tid == 0) out[BD] = mv;                                               // mask_norm
        }
        if (tid == 0) out[BD + 1] = sqrtf((part[0] + part[1]) + (part[2] + part[3])); // embed_norm
        return;
    }
    int rowv = blockIdx.x * 4 + (tid >> 6);   // 4096 rows, wave per row
    int lane = tid & 63;
    float4* p = (float4*)out + (size_t)rowv * 64 + lane;
    float4 v = *p;
    float s = v.x * v.x + v.y * v.y + v.z * v.z + v.w * v.w;
    s = wave_reduce_sum(s);
    float inv = 1.0f / fmaxf(sqrtf(s), 1e-10f);
    v.x *= inv; v.y *= inv; v.z *= inv; v.w *= inv;
    *p = v;
}

extern "C" void kernel_launch(void* const* d_in, const int* in_sizes, int n_in,
                              void* d_out, int out_size, void* d_ws, size_t ws_size,
                              hipStream_t stream) {
    const float* x = (const float*)d_in[0];
    const float* W = (const float*)d_in[1];
    const float* b = (const float*)d_in[2];
    const int*   c = (const int*)d_in[3];
    float* out = (float*)d_out;

    float* xsqp = (float*)d_ws;           // 512
    float* l1p  = xsqp + 512;             // 256
    int*   cnt2 = (int*)(l1p + 256);      // 128

    k_main<<<512, 256, 0, stream>>>(W, b, x, c, out, l1p, xsqp, cnt2);
    k_finish<<<1025, 256, 0, stream>>>(out, xsqp, l1p, cnt2);
}